// Round 2
// baseline (85.167 us; speedup 1.0000x reference)
//
#include <hip/hip_runtime.h>
#include <hip/hip_bf16.h>

// Problem constants: B=2, H=8, L=2048, D=64  (fp32 in, fp32 out)
#define BHN    16          // B*H
#define LSEQ   2048
#define DDIM   64
#define CHUNK  128         // l-rows per K1 block
#define NCHUNK (LSEQ / CHUNK)   // 16
#define NPART  (BHN * NCHUNK)   // 256 partial M-tiles

typedef unsigned short ushort8 __attribute__((ext_vector_type(8)));
typedef __bf16        bf16x8  __attribute__((ext_vector_type(8)));
typedef float         f32x4   __attribute__((ext_vector_type(4)));

// float -> bf16 bits, round-to-nearest-even
__device__ __forceinline__ unsigned short f2bf(float f) {
    unsigned int u = __float_as_uint(f);
    u = u + 0x7FFFu + ((u >> 16) & 1u);
    return (unsigned short)(u >> 16);
}

// ---------------------------------------------------------------------------
// K1: partial M^T = (K^T V)^T per (bh, chunk).  P[pid][d2*64+d1] fp32.
// ---------------------------------------------------------------------------
__global__ __launch_bounds__(256) void k1_ktv(const float* __restrict__ Km,
                                              const float* __restrict__ Vm,
                                              float* __restrict__ P) {
    __shared__ float smem[16384];                 // 64 KB
    float* K_s = smem;                            // [128][64]
    float* V_s = smem + CHUNK * DDIM;             // [128][64]

    const int pid   = blockIdx.x;                 // 0..255
    const int bh    = pid >> 4;
    const int chunk = pid & 15;
    const int t     = threadIdx.x;

    const float* Kbase = Km + (size_t)bh * LSEQ * DDIM + (size_t)chunk * CHUNK * DDIM;
    const float* Vbase = Vm + (size_t)bh * LSEQ * DDIM + (size_t)chunk * CHUNK * DDIM;

    // stage K,V chunk (coalesced float4)
    #pragma unroll
    for (int i = 0; i < 8; ++i) {
        int f4 = t + i * 256;
        ((float4*)K_s)[f4] = ((const float4*)Kbase)[f4];
        ((float4*)V_s)[f4] = ((const float4*)Vbase)[f4];
    }
    __syncthreads();

    const int w    = t >> 6;
    const int lane = t & 63;
    const int a    = lane & 7;    // d1 block (x8)
    const int b    = lane >> 3;   // d2 block (x8)

    float acc[8][8];              // acc[j2 (d2)][j1 (d1)]
    #pragma unroll
    for (int i = 0; i < 8; ++i)
        #pragma unroll
        for (int j = 0; j < 8; ++j) acc[i][j] = 0.f;

    const float* Kw = K_s + (w * 32) * DDIM;
    const float* Vw = V_s + (w * 32) * DDIM;

    #pragma unroll 2
    for (int l = 0; l < 32; ++l) {
        float4 k0 = *(const float4*)(Kw + l * DDIM + a * 8);
        float4 k1 = *(const float4*)(Kw + l * DDIM + a * 8 + 4);
        float4 v0 = *(const float4*)(Vw + l * DDIM + b * 8);
        float4 v1 = *(const float4*)(Vw + l * DDIM + b * 8 + 4);
        float kk[8] = {k0.x, k0.y, k0.z, k0.w, k1.x, k1.y, k1.z, k1.w};
        float vv[8] = {v0.x, v0.y, v0.z, v0.w, v1.x, v1.y, v1.z, v1.w};
        #pragma unroll
        for (int j2 = 0; j2 < 8; ++j2)
            #pragma unroll
            for (int j1 = 0; j1 < 8; ++j1)
                acc[j2][j1] = fmaf(kk[j1], vv[j2], acc[j2][j1]);
    }
    __syncthreads();   // done reading K_s/V_s; reuse smem as reduce buffer

    // per-wave partial -> LDS, XOR-swizzled so same-j2 stores hit distinct slots
    float* R = smem;   // [4][64][64]
    #pragma unroll
    for (int j2 = 0; j2 < 8; ++j2) {
        int row = b * 8 + j2;            // d2
        int pc  = (a ^ j2) * 8;          // swizzled d1 col-group (row&7 == j2)
        float* dst = R + w * 4096 + row * 64 + pc;
        *(float4*)(dst)     = float4{acc[j2][0], acc[j2][1], acc[j2][2], acc[j2][3]};
        *(float4*)(dst + 4) = float4{acc[j2][4], acc[j2][5], acc[j2][6], acc[j2][7]};
    }
    __syncthreads();

    // cross-wave reduce + global store (coalesced)
    float* Pout = P + (size_t)pid * 4096;
    #pragma unroll
    for (int i = 0; i < 16; ++i) {
        int e   = t + i * 256;
        int row = e >> 6;
        int col = e & 63;
        int pcc = col ^ ((row & 7) << 3);
        int idx = row * 64 + pcc;
        float s = R[idx] + R[4096 + idx] + R[8192 + idx] + R[12288 + idx];
        Pout[e] = s;
    }
}

// ---------------------------------------------------------------------------
// K2: reduce 16 chunk-partials per bh -> MT bf16 [bh][d2][d1]
// ---------------------------------------------------------------------------
__global__ __launch_bounds__(256) void k2_reduce(const float* __restrict__ P,
                                                 unsigned short* __restrict__ MT) {
    const int blk = blockIdx.x;          // 0..255
    const int bh  = blk >> 4;
    const int seg = blk & 15;
    const int e   = seg * 256 + threadIdx.x;
    float s = 0.f;
    #pragma unroll
    for (int c = 0; c < 16; ++c)
        s += P[(size_t)(bh * 16 + c) * 4096 + e];
    MT[(size_t)bh * 4096 + e] = f2bf(s);
}

// ---------------------------------------------------------------------------
// K3: out = Q @ M  via mfma_f32_16x16x32_bf16.  A from Q, B from MT (both
// contraction-contiguous, no LDS).  Wave owns 16 q-rows x 64 d2.
// ---------------------------------------------------------------------------
__global__ __launch_bounds__(256) void k3_qm(const float* __restrict__ Q,
                                             const unsigned short* __restrict__ MT,
                                             float* __restrict__ Out) {
    const int pid  = blockIdx.x;         // 0..511
    const int bh   = pid >> 5;
    const int rb   = pid & 31;
    const int t    = threadIdx.x;
    const int w    = t >> 6;
    const int lane = t & 63;
    const int q0   = rb * 64 + w * 16;   // wave's first q row
    const int r    = lane & 15;
    const int g    = lane >> 4;

    const float* Qb = Q + (size_t)bh * LSEQ * DDIM;

    union Frag { ushort8 u; bf16x8 b; };
    Frag afrag[2];
    #pragma unroll
    for (int s = 0; s < 2; ++s) {
        const float* qp = Qb + (size_t)(q0 + r) * DDIM + s * 32 + g * 8;
        float4 x0 = *(const float4*)qp;
        float4 x1 = *(const float4*)(qp + 4);
        afrag[s].u = (ushort8){f2bf(x0.x), f2bf(x0.y), f2bf(x0.z), f2bf(x0.w),
                               f2bf(x1.x), f2bf(x1.y), f2bf(x1.z), f2bf(x1.w)};
    }

    const unsigned short* Mb = MT + (size_t)bh * 4096;
    f32x4 acc[4];
    #pragma unroll
    for (int nt = 0; nt < 4; ++nt) {
        acc[nt] = (f32x4){0.f, 0.f, 0.f, 0.f};
        #pragma unroll
        for (int s = 0; s < 2; ++s) {
            Frag bfrag;
            bfrag.u = *(const ushort8*)(Mb + (nt * 16 + r) * 64 + s * 32 + g * 8);
            acc[nt] = __builtin_amdgcn_mfma_f32_16x16x32_bf16(afrag[s].b, bfrag.b,
                                                              acc[nt], 0, 0, 0);
        }
    }

    float* Ob = Out + (size_t)bh * LSEQ * DDIM;
    #pragma unroll
    for (int nt = 0; nt < 4; ++nt)
        #pragma unroll
        for (int j = 0; j < 4; ++j)
            Ob[(size_t)(q0 + g * 4 + j) * DDIM + nt * 16 + r] = acc[nt][j];
}

// ---------------------------------------------------------------------------
extern "C" void kernel_launch(void* const* d_in, const int* in_sizes, int n_in,
                              void* d_out, int out_size, void* d_ws, size_t ws_size,
                              hipStream_t stream) {
    const float* q = (const float*)d_in[0];
    const float* k = (const float*)d_in[1];
    const float* v = (const float*)d_in[2];
    float* out = (float*)d_out;

    float*          P  = (float*)d_ws;                                   // 4 MB
    unsigned short* MT = (unsigned short*)((char*)d_ws +
                          (size_t)NPART * 4096 * sizeof(float));         // 128 KB

    k1_ktv   <<<NPART, 256, 0, stream>>>(k, v, P);
    k2_reduce<<<256,   256, 0, stream>>>(P, MT);
    k3_qm    <<<BHN * 32, 256, 0, stream>>>(q, MT, out);
}